// Round 21
// baseline (663.728 us; speedup 1.0000x reference)
//
#include <hip/hip_runtime.h>
#include <stdint.h>

// ---------- types ----------
typedef __attribute__((ext_vector_type(8))) __bf16 bf16x8;
typedef __attribute__((ext_vector_type(4))) float f32x4;
typedef __attribute__((ext_vector_type(16))) float f32x16;
typedef __attribute__((ext_vector_type(8))) unsigned short ushort8;

// ---------- helpers ----------
__device__ __forceinline__ unsigned short f2bf(float f){
  union { float f; unsigned int i; } v; v.f = f;
  unsigned int r = v.i + 0x7fffu + ((v.i >> 16) & 1u);   // RNE
  return (unsigned short)(r >> 16);
}
__device__ __forceinline__ void gload16(const void* g, void* l){
  __builtin_amdgcn_global_load_lds((__attribute__((address_space(1))) void*)(g),
                                   (__attribute__((address_space(3))) void*)(l),
                                   16, 0, 0);
}
__device__ __forceinline__ unsigned int cvtpk(float lo, float hi){
  unsigned int r;
  asm("v_cvt_pk_bf16_f32 %0, %1, %2" : "=v"(r) : "v"(lo), "v"(hi));
  return r;
}
// single-instruction 2^x (OCML exp2f is a multi-instr libm call)
__device__ __forceinline__ float fexp2(float x){
  float r; asm("v_exp_f32 %0, %1" : "=v"(r) : "v"(x)); return r;
}
// swizzled LDS read of a 16B chunk from a [64][64] bf16 tile (128B rows)
__device__ __forceinline__ bf16x8 ldsw(const char* tile, int row, int colb){
  return *(const bf16x8*)(tile + row*128 + (colb ^ ((row & 7) << 4)));
}

// ---------- constants ----------
#define SEQ   2048
#define DM    1024
#define NH    16
#define DK    64
#define BATCH 4
#define MTOT  (BATCH*SEQ)          // 8192
#define NX    (MTOT*DM)            // 8388608 elements in x
#define NW    (DM*DM)              // 1048576 per weight

#define QSCALE 0.18033688011112f   // (1/8) * log2(e)  -> softmax in exp2 domain

// ============================================================
// fused convert + tables
// ============================================================
__global__ __launch_bounds__(256) void k_convert(
    const float* __restrict__ x,  const float* __restrict__ wq,
    const float* __restrict__ wk, const float* __restrict__ wv,
    const float* __restrict__ wo,
    unsigned short* __restrict__ xb, unsigned short* __restrict__ wb,
    const int* __restrict__ pos, float* __restrict__ tab)
{
  const int tid = blockIdx.x * 256 + threadIdx.x;    // 1638400 threads
  if (tid < 1572864){
    const long long e = (long long)tid * 8;
    const float* src; unsigned short* dst;
    if (e < NX) { src = x + e; dst = xb + e; }
    else {
      long long j = e - NX;
      int seg = (int)(j >> 20);            // /1048576
      long long off = j & 1048575;
      src = (seg==0?wq:seg==1?wk:seg==2?wv:wo) + off;
      dst = wb + (size_t)seg*NW + off;
    }
    const float4 a = *(const float4*)src;
    const float4 b = *(const float4*)(src + 4);
    uint4 o;
    o.x = (unsigned int)f2bf(a.x) | ((unsigned int)f2bf(a.y) << 16);
    o.y = (unsigned int)f2bf(a.z) | ((unsigned int)f2bf(a.w) << 16);
    o.z = (unsigned int)f2bf(b.x) | ((unsigned int)f2bf(b.y) << 16);
    o.w = (unsigned int)f2bf(b.z) | ((unsigned int)f2bf(b.w) << 16);
    *(uint4*)dst = o;
  } else {
    const int idx = tid - 1572864;                   // 0..65535
    const int s = idx >> 5, i = idx & 31;
    const float inv = __expf(-0.28782313662425575f * (float)i);
    const float a = (float)pos[s] * inv;
    tab[2*idx]   = cosf(a);
    tab[2*idx+1] = sinf(a);
  }
}

// ============================================================
// NT GEMM, BK=32, DOUBLE buffer 2x24KB=48KB -> 3 blocks/CU
// (6 waves/SIMD), ONE barrier per K-tile, depth-1 prefetch with
// vmcnt(0) boundary (drain covered by the +50% TLP — R21 A/B vs
// R20's counted-vmcnt at 2 blocks/CU).
// Per tile: {8 ds_reads (all frags) || 3 stage issues for t+1 ->
// 16 MFMA -> vmcnt(0) -> s_barrier}. 64B fragment rows with R11's
// conflict-free swizzle c ^= (row>>1)&3 (source + read).
// Epilogue: four 64x128 fp32 LDS quarters (32KB), coalesced
// RoPE / transposed V^T / fp32 rows.
// ============================================================
#define NT32 32
#define ABUF32  16384    // 256*32*2B
#define BSTR32  24576    // A 16K + B 8K

template<int MODE>
__global__ __launch_bounds__(512, 6) void k_gemm(
    const unsigned short* __restrict__ A,
    const unsigned short* __restrict__ Wb,
    unsigned short* __restrict__ D0,
    unsigned short* __restrict__ D1,
    unsigned short* __restrict__ D2,
    float* __restrict__ Dout,
    const float* __restrict__ tab)
{
  __shared__ __attribute__((aligned(16))) char lds_[2*BSTR32];   // 48 KB
  const int tid  = threadIdx.x;
  const int lane = tid & 63;
  const int w    = tid >> 6;          // 0..7
  const int wm = w >> 1, wn = w & 1;  // 4M x 2N

  // T1 XCD-aware decode
  const int bid = blockIdx.x;
  const int tq  = bid >> 3;
  const int m0  = ((bid & 7)*4 + (tq & 3)) * 256;
  const int r   = tq >> 2;
  const int n0  = (MODE == 0 ? (r & 7) : r) * 128;
  const int z   = (MODE == 0) ? (r >> 3) : 0;

  const unsigned short* W = Wb + (size_t)z * NW;
  unsigned short* Dh = (MODE == 0) ? ((z == 0) ? D0 : (z == 1) ? D1 : D2) : nullptr;
  const bool vtr = (MODE == 0) && (z == 2);

  f32x4 acc[4][4];
  #pragma unroll
  for (int i = 0; i < 4; ++i)
    #pragma unroll
    for (int j = 0; j < 4; ++j)
      acc[i][j] = (f32x4)0.0f;

  auto stA = [&](int buf, int t, int l){
    const int id = l*512 + tid;                 // 0..1023
    const int row = id >> 2, c = id & 3;
    gload16(A + (size_t)(m0 + row)*DM + t*32 + ((c ^ ((row >> 1) & 3)) << 3),
            lds_ + buf*BSTR32 + id*16);
  };
  auto stB = [&](int buf, int t){
    const int id = tid;                         // 0..511
    const int row = id >> 2, c = id & 3;
    gload16(W + (size_t)(n0 + row)*DM + t*32 + ((c ^ ((row >> 1) & 3)) << 3),
            lds_ + buf*BSTR32 + ABUF32 + id*16);
  };
  auto ldA = [&](const char* Ab_, int i){
    const int row = wm*64 + i*16 + (lane & 15);
    const int c = (lane >> 4) ^ ((row >> 1) & 3);
    return *(const bf16x8*)(Ab_ + row*64 + (c << 4));
  };
  auto ldB = [&](const char* Bb_, int j){
    const int row = wn*64 + j*16 + (lane & 15);
    const int c = (lane >> 4) ^ ((row >> 1) & 3);
    return *(const bf16x8*)(Bb_ + row*64 + (c << 4));
  };

  // prologue: stage tile 0; drain; barrier
  stA(0, 0, 0); stA(0, 0, 1); stB(0, 0);
  asm volatile("s_waitcnt vmcnt(0)" ::: "memory");
  __builtin_amdgcn_s_barrier();

  for (int t = 0; t < NT32; ++t){
    const char* Ab_ = lds_ + (t & 1)*BSTR32;
    const char* Bb_ = Ab_ + ABUF32;
    const int nb = (t + 1) & 1;
    const bool st = (t + 1 < NT32);
    bf16x8 aF[4], bF[4];

    // all 8 fragment reads + prefetch(t+1) issues, then one MFMA cluster
    aF[0] = ldA(Ab_, 0); aF[1] = ldA(Ab_, 1);
    aF[2] = ldA(Ab_, 2); aF[3] = ldA(Ab_, 3);
    bF[0] = ldB(Bb_, 0); bF[1] = ldB(Bb_, 1);
    bF[2] = ldB(Bb_, 2); bF[3] = ldB(Bb_, 3);
    if (st){ stA(nb, t+1, 0); stA(nb, t+1, 1); stB(nb, t+1); }
    __builtin_amdgcn_s_setprio(1);
    #pragma unroll
    for (int i = 0; i < 4; ++i)
      #pragma unroll
      for (int j = 0; j < 4; ++j)
        acc[i][j] = __builtin_amdgcn_mfma_f32_16x16x32_bf16(aF[i], bF[j], acc[i][j], 0, 0, 0);
    __builtin_amdgcn_s_setprio(0);
    if (st){
      asm volatile("s_waitcnt vmcnt(0)" ::: "memory");
      __builtin_amdgcn_s_barrier();
    }
  }

  // ---- epilogue: four 64x128 fp32 LDS quarters (32KB) ----
  __syncthreads();
  float* T = (float*)lds_;
  #pragma unroll
  for (int h = 0; h < 4; ++h){
    if (h) __syncthreads();          // previous quarter's reads done
    if (wm == h){
      #pragma unroll
      for (int i = 0; i < 4; ++i)
        #pragma unroll
        for (int j = 0; j < 4; ++j){
          const int n = wn*64 + j*16 + (lane & 15);
          #pragma unroll
          for (int rr = 0; rr < 4; ++rr){
            const int ml = i*16 + ((lane >> 4) << 2) + rr;   // 0..63
            T[ml*128 + (n ^ ((ml & 7) << 2))] = acc[i][j][rr];
          }
        }
    }
    __syncthreads();
    if (MODE == 0 && vtr){
      // transposed coalesced V^T: thread owns column, 16B s-runs
      const int nl = tid >> 2;               // 0..127
      const int sblk = tid & 3;
      const int d = nl & 63, hh = (n0 >> 6) + (nl >> 6);
      const int bidx = m0 >> 11;
      unsigned short* vrow = Dh + (((size_t)(bidx*NH + hh))*DK + d)*SEQ
                               + (m0 & 2047) + h*64;
      #pragma unroll
      for (int c = 0; c < 2; ++c){
        const int s0 = sblk*8 + c*32;
        float v[8];
        #pragma unroll
        for (int j2 = 0; j2 < 8; ++j2)
          v[j2] = T[(s0 + j2)*128 + (nl ^ (((s0 + j2) & 7) << 2))];
        uint4 ov;
        ov.x = cvtpk(v[0], v[1]); ov.y = cvtpk(v[2], v[3]);
        ov.z = cvtpk(v[4], v[5]); ov.w = cvtpk(v[6], v[7]);
        *(uint4*)(vrow + s0) = ov;
      }
    } else {
      const float scale = (MODE == 0 && z == 0) ? QSCALE : 1.0f;
      #pragma unroll
      for (int k = 0; k < 2; ++k){
        const int cid = k*512 + tid;         // 0..1023
        const int d8   = cid & 7;            // 8-wide n-chunk within head
        const int sp_l = (cid >> 3) & 63;    // local row in quarter
        const int hc   = cid >> 9;           // head half (0/1)
        const int nb2  = hc*64 + d8*8;
        const int sw   = (sp_l & 7) << 2;
        const f32x4 c0 = *(const f32x4*)&T[sp_l*128 + (nb2 ^ sw)];
        const f32x4 c1 = *(const f32x4*)&T[sp_l*128 + ((nb2 + 4) ^ sw)];
        if (MODE == 1){
          float* dst = Dout + (size_t)(m0 + h*64 + sp_l)*DM + n0 + nb2;
          *(f32x4*)dst = c0;
          *(f32x4*)(dst + 4) = c1;
        } else {
          const int mg = m0 + h*64 + sp_l;
          const int bidx = mg >> 11, sp = mg & 2047;
          const float4 t01 = *(const float4*)&tab[(size_t)sp*64 + d8*8];
          const float4 t23 = *(const float4*)&tab[(size_t)sp*64 + d8*8 + 4];
          const unsigned int u0 = cvtpk((t01.x*c0[0] - t01.y*c0[1])*scale,
                                        (t01.y*c0[0] + t01.x*c0[1])*scale);
          const unsigned int u1 = cvtpk((t01.z*c0[2] - t01.w*c0[3])*scale,
                                        (t01.w*c0[2] + t01.z*c0[3])*scale);
          const unsigned int u2 = cvtpk((t23.x*c1[0] - t23.y*c1[1])*scale,
                                        (t23.y*c1[0] + t23.x*c1[1])*scale);
          const unsigned int u3 = cvtpk((t23.z*c1[2] - t23.w*c1[3])*scale,
                                        (t23.w*c1[2] + t23.z*c1[3])*scale);
          const int hh = (n0 >> 6) + hc;
          uint4 ov; ov.x = u0; ov.y = u1; ov.z = u2; ov.w = u3;
          *(uint4*)(Dh + ((size_t)((bidx*NH + hh)*SEQ + sp))*DK + d8*8) = ov;
        }
      }
    }
  }
}

// ============================================================
// Causal flash attention — swapped-QK^T 32x32 in-register softmax,
// kv-split dual-group blocks (8 waves, 512 threads), STATIC-MAX,
// v_exp_f32, XCD-pinned (bh,jj) grid. (frozen from R18)
// ============================================================
__global__ __launch_bounds__(512, 4) void k_attn(const unsigned short* __restrict__ Qh,
                                                 const unsigned short* __restrict__ Kh,
                                                 const unsigned short* __restrict__ Vt,
                                                 unsigned short* __restrict__ Ab)
{
  __shared__ uint4 ldsu[4096];   // 64 KiB: per-group [K0 8K|V0 8K][K1 8K|V1 8K]
  char* base = (char*)ldsu;
  const int tid  = threadIdx.x;
  const int lane = tid & 63;
  const int w    = tid >> 6;     // 0..7
  const int ww   = w & 3;        // wave-in-group
  const int g    = w >> 2;       // kv-half group
  const int tl   = tid & 255;    // thread-in-group
  const int l31  = lane & 31;
  const int hl   = lane >> 5;
  char* gb = base + g*32768;

  const int bh = blockIdx.x, jj = blockIdx.y;   // bh fast -> XCD-pinned KV
  const unsigned short* Qb = Qh + (size_t)bh*(SEQ*DK);
  const unsigned short* Kb = Kh + (size_t)bh*(SEQ*DK);
  const unsigned short* Vb = Vt + (size_t)bh*(SEQ*DK);
  const int b = bh >> 4, hd = bh & 15;

  for (int pass = 0; pass < 2; ++pass){
    const int qt = pass ? jj : 15 - jj;
    const int q0 = qt * 128;
    const int qbase = q0 + ww*32;

    bf16x8 qf[4];
    #pragma unroll
    for (int t = 0; t < 4; ++t)
      qf[t] = *(const bf16x8*)(Qb + (size_t)(qbase + l31)*DK + t*16 + hl*8);

    f32x16 acc0 = (f32x16)0.0f, acc1 = (f32x16)0.0f;
    float lsum = 0.0f;

    const int nk = qt + 1;
    const int tbase = g * nk;
    const int wqmax = qbase + 31;

    auto stage = [&](int buf, int ktile){
      const int k0s = ktile * 64;
      char* Kd = gb + buf*16384;
      char* Vd = Kd + 8192;
      #pragma unroll
      for (int cc = 0; cc < 2; ++cc){
        const int f = cc*256 + tl;
        const int r = f >> 3, slot = f & 7;
        const int sw = ((slot ^ (r & 7)) << 3);
        gload16(Kb + (size_t)(k0s + r)*DK + sw, Kd + (cc*256 + ww*64)*16);
        gload16(Vb + (size_t)r*SEQ + k0s + sw, Vd + (cc*256 + ww*64)*16);
      }
    };

    if (pass) __syncthreads();
    stage(0, tbase);
    __syncthreads();
    int cur = 0;

    for (int kt = 0; kt < nk; ++kt){
      const int k0 = (tbase + kt) * 64;
      if (kt + 1 < nk) stage(cur ^ 1, tbase + kt + 1);
      if (k0 <= wqmax){
        const char* Ks = gb + cur*16384;
        const char* Vs = Ks + 8192;

        f32x16 sv0 = (f32x16)0.0f, sv1 = (f32x16)0.0f;
        __builtin_amdgcn_s_setprio(1);
        #pragma unroll
        for (int t = 0; t < 4; ++t){
          const int colb = t*32 + hl*16;
          const bf16x8 a0 = ldsw(Ks, l31, colb);
          const bf16x8 a1 = ldsw(Ks, 32 + l31, colb);
          sv0 = __builtin_amdgcn_mfma_f32_32x32x16_bf16(a0, qf[t], sv0, 0, 0, 0);
          sv1 = __builtin_amdgcn_mfma_f32_32x32x16_bf16(a1, qf[t], sv1, 0, 0, 0);
        }
        __builtin_amdgcn_s_setprio(0);

        if (k0 + 63 > qbase){
          const int q = qbase + l31;
          #pragma unroll
          for (int j = 0; j < 16; ++j){
            const int kv = k0 + (j&3) + 8*(j>>2) + 4*hl;
            if (kv > q)      sv0[j] = -1e30f;
            if (kv + 32 > q) sv1[j] = -1e30f;
          }
        }

        #pragma unroll
        for (int j = 0; j < 16; ++j){
          sv0[j] = fexp2(sv0[j]);
          sv1[j] = fexp2(sv1[j]);
        }
        float ts[8];
        #pragma unroll
        for (int j = 0; j < 8; ++j)
          ts[j] = (sv0[j] + sv0[j+8]) + (sv1[j] + sv1[j+8]);
        #pragma unroll
        for (int off = 4; off; off >>= 1)
          #pragma unroll
          for (int j = 0; j < off; ++j)
            ts[j] += ts[j+off];
        lsum += ts[0] + __shfl_xor(ts[0], 32, 64);

        __builtin_amdgcn_s_setprio(1);
        #pragma unroll
        for (int t = 0; t < 4; ++t){
          f32x16& s = (t < 2) ? sv0 : sv1;
          const int b0v = (t & 1) * 8;
          const unsigned int A0 = cvtpk(s[b0v+0], s[b0v+1]);
          const unsigned int A1 = cvtpk(s[b0v+2], s[b0v+3]);
          const unsigned int B0 = cvtpk(s[b0v+4], s[b0v+5]);
          const unsigned int B1 = cvtpk(s[b0v+6], s[b0v+7]);
          const unsigned int s0 = hl ? A0 : B0;
          const unsigned int s1 = hl ? A1 : B1;
          const unsigned int r0 = (unsigned int)__shfl_xor((int)s0, 32, 64);
          const unsigned int r1 = (unsigned int)__shfl_xor((int)s1, 32, 64);
          union { unsigned int u[4]; bf16x8 v; } f;
          f.u[0] = hl ? r0 : A0; f.u[1] = hl ? r1 : A1;
          f.u[2] = hl ? B0 : r0; f.u[3] = hl ? B1 : r1;
          const int colb = t*32 + hl*16;
          const bf16x8 v0 = ldsw(Vs, l31, colb);
          const bf16x8 v1 = ldsw(Vs, 32 + l31, colb);
          acc0 = __builtin_amdgcn_mfma_f32_32x32x16_bf16(v0, f.v, acc0, 0, 0, 0);
          acc1 = __builtin_amdgcn_mfma_f32_32x32x16_bf16(v1, f.v, acc1, 0, 0, 0);
        }
        __builtin_amdgcn_s_setprio(0);
      }
      __syncthreads();
      cur ^= 1;
    }

    if (g == 1){
      char* cw = base + ww*9216 + lane*144;
      #pragma unroll
      for (int q4 = 0; q4 < 4; ++q4){
        *(f32x4*)(cw + q4*16)      = (f32x4){acc0[4*q4], acc0[4*q4+1], acc0[4*q4+2], acc0[4*q4+3]};
        *(f32x4*)(cw + 64 + q4*16) = (f32x4){acc1[4*q4], acc1[4*q4+1], acc1[4*q4+2], acc1[4*q4+3]};
      }
      *(float*)(cw + 128) = lsum;
    }
    __syncthreads();
    if (g == 0){
      const char* cr = base + ww*9216 + lane*144;
      const float l1 = *(const float*)(cr + 128);
      const float linv = 1.0f / (lsum + l1);
      unsigned short* orow = Ab + ((size_t)(b*SEQ + qbase + l31))*DM + hd*DK;
      #pragma unroll
      for (int mt = 0; mt < 2; ++mt){
        #pragma unroll
        for (int g4 = 0; g4 < 4; ++g4){
          const f32x16& a = mt ? acc1 : acc0;
          const f32x4 o = *(const f32x4*)(cr + mt*64 + g4*16);
          const unsigned int u0 = cvtpk((a[4*g4+0] + o[0])*linv, (a[4*g4+1] + o[1])*linv);
          const unsigned int u1 = cvtpk((a[4*g4+2] + o[2])*linv, (a[4*g4+3] + o[3])*linv);
          *(unsigned long long*)(orow + mt*32 + g4*8 + hl*4) =
              (unsigned long long)u0 | ((unsigned long long)u1 << 32);
        }
      }
    }
  }
}

// ============================================================
// launch
// ============================================================
extern "C" void kernel_launch(void* const* d_in, const int* in_sizes, int n_in,
                              void* d_out, int out_size, void* d_ws, size_t ws_size,
                              hipStream_t stream)
{
  (void)in_sizes; (void)n_in; (void)out_size;
  const float* x  = (const float*)d_in[0];
  const float* wq = (const float*)d_in[1];
  const float* wk = (const float*)d_in[2];
  const float* wv = (const float*)d_in[3];
  const float* wo = (const float*)d_in[4];
  const int* pos  = (const int*)d_in[5];
  float* out = (float*)d_out;

  // workspace layout (bytes); Ab (attn out) aliases xb (x no longer needed)
  if (ws_size < 92800000u) return;   // need ~88.5 MB
  char* ws = (char*)d_ws;
  unsigned short* xb = (unsigned short*)(ws);                 // 16 MB (also Ab)
  unsigned short* wb = (unsigned short*)(ws + 16777216);      //  8 MB (Wq|Wk|Wv|Wo)
  unsigned short* Qh = (unsigned short*)(ws + 25165824);      // 16 MB [b][h][s][d]
  unsigned short* Kh = (unsigned short*)(ws + 41943040);      // 16 MB
  unsigned short* Vt = (unsigned short*)(ws + 75497472);      // 16 MB [b][h][d][s]
  float* tab         = (float*)(ws + 92274688);               // 512 KB

  k_convert <<<6400, 256, 0, stream>>>(x, wq, wk, wv, wo, xb, wb, pos, tab);
  k_gemm<0> <<<768, 512, 0, stream>>>(xb, wb, Qh, Kh, Vt, nullptr, tab);
  k_attn    <<<dim3(64, 8), 512, 0, stream>>>(Qh, Kh, Vt, xb);
  k_gemm<1> <<<256, 512, 0, stream>>>(xb, wb + 3*NW, nullptr, nullptr,
                                      nullptr, out, nullptr);
}

// Round 22
// 153.124 us; speedup vs baseline: 4.3346x; 4.3346x over previous
//
#include <hip/hip_runtime.h>
#include <stdint.h>

// ---------- types ----------
typedef __attribute__((ext_vector_type(8))) __bf16 bf16x8;
typedef __attribute__((ext_vector_type(4))) float f32x4;
typedef __attribute__((ext_vector_type(16))) float f32x16;
typedef __attribute__((ext_vector_type(8))) unsigned short ushort8;

// ---------- helpers ----------
__device__ __forceinline__ unsigned short f2bf(float f){
  union { float f; unsigned int i; } v; v.f = f;
  unsigned int r = v.i + 0x7fffu + ((v.i >> 16) & 1u);   // RNE
  return (unsigned short)(r >> 16);
}
__device__ __forceinline__ void gload16(const void* g, void* l){
  __builtin_amdgcn_global_load_lds((__attribute__((address_space(1))) void*)(g),
                                   (__attribute__((address_space(3))) void*)(l),
                                   16, 0, 0);
}
__device__ __forceinline__ unsigned int cvtpk(float lo, float hi){
  unsigned int r;
  asm("v_cvt_pk_bf16_f32 %0, %1, %2" : "=v"(r) : "v"(lo), "v"(hi));
  return r;
}
// single-instruction 2^x (OCML exp2f is a multi-instr libm call)
__device__ __forceinline__ float fexp2(float x){
  float r; asm("v_exp_f32 %0, %1" : "=v"(r) : "v"(x)); return r;
}
// swizzled LDS read of a 16B chunk from a [64][64] bf16 tile (128B rows)
__device__ __forceinline__ bf16x8 ldsw(const char* tile, int row, int colb){
  return *(const bf16x8*)(tile + row*128 + (colb ^ ((row & 7) << 4)));
}

// ---------- constants ----------
#define SEQ   2048
#define DM    1024
#define NH    16
#define DK    64
#define BATCH 4
#define MTOT  (BATCH*SEQ)          // 8192
#define NX    (MTOT*DM)            // 8388608 elements in x
#define NW    (DM*DM)              // 1048576 per weight

#define QSCALE 0.18033688011112f   // (1/8) * log2(e)  -> softmax in exp2 domain

// ============================================================
// fused convert + tables:
// tid < 1572864: fp32->bf16 convert, 32B/thread (x then Wq,Wk,Wv,Wo)
// else: sin/cos table, 1 entry/thread (65536 entries)
// ============================================================
__global__ __launch_bounds__(256) void k_convert(
    const float* __restrict__ x,  const float* __restrict__ wq,
    const float* __restrict__ wk, const float* __restrict__ wv,
    const float* __restrict__ wo,
    unsigned short* __restrict__ xb, unsigned short* __restrict__ wb,
    const int* __restrict__ pos, float* __restrict__ tab)
{
  const int tid = blockIdx.x * 256 + threadIdx.x;    // 1638400 threads
  if (tid < 1572864){
    const long long e = (long long)tid * 8;
    const float* src; unsigned short* dst;
    if (e < NX) { src = x + e; dst = xb + e; }
    else {
      long long j = e - NX;
      int seg = (int)(j >> 20);            // /1048576
      long long off = j & 1048575;
      src = (seg==0?wq:seg==1?wk:seg==2?wv:wo) + off;
      dst = wb + (size_t)seg*NW + off;
    }
    const float4 a = *(const float4*)src;
    const float4 b = *(const float4*)(src + 4);
    uint4 o;
    o.x = (unsigned int)f2bf(a.x) | ((unsigned int)f2bf(a.y) << 16);
    o.y = (unsigned int)f2bf(a.z) | ((unsigned int)f2bf(a.w) << 16);
    o.z = (unsigned int)f2bf(b.x) | ((unsigned int)f2bf(b.y) << 16);
    o.w = (unsigned int)f2bf(b.z) | ((unsigned int)f2bf(b.w) << 16);
    *(uint4*)dst = o;
  } else {
    const int idx = tid - 1572864;                   // 0..65535
    const int s = idx >> 5, i = idx & 31;
    const float inv = __expf(-0.28782313662425575f * (float)i);
    const float a = (float)pos[s] * inv;
    tab[2*idx]   = cosf(a);
    tab[2*idx+1] = sinf(a);
  }
}

// ============================================================
// NT GEMM, BK=32, 2 blocks/CU, ONE barrier per K-tile:
// 256x128 tile, NT=32, triple buffer 3x24KB=72KB, counted vmcnt(3)
// (depth-2 prefetch). Per tile: {8 ds_reads (all frags) || 3 stage
// issues -> 16 MFMA -> vmcnt(3) -> s_barrier}. WAR on buffer
// (t+2)%3 is safe: every wave's ds_reads retire (lgkm) before its
// MFMAs, which precede barrier t. 64B fragment rows use R11's
// verified conflict-free swizzle c ^= (row>>1)&3 (source + read).
// Epilogue: two 128x128 fp32 LDS halves, coalesced RoPE / V^T / f32.
// (R20 configuration — best measured 153.6 us total. R21's
// launch_bounds(512,6) experiment spilled acc to scratch: VGPR 40,
// 806MB FETCH — 3 blocks/CU is register-infeasible at this tile.)
// ============================================================
#define NT32 32
#define ABUF32  16384    // 256*32*2B
#define BSTR32  24576    // A 16K + B 8K

template<int MODE>
__global__ __launch_bounds__(512, 4) void k_gemm(
    const unsigned short* __restrict__ A,
    const unsigned short* __restrict__ Wb,
    unsigned short* __restrict__ D0,
    unsigned short* __restrict__ D1,
    unsigned short* __restrict__ D2,
    float* __restrict__ Dout,
    const float* __restrict__ tab)
{
  __shared__ __attribute__((aligned(16))) char lds_[3*BSTR32];   // 72 KB
  const int tid  = threadIdx.x;
  const int lane = tid & 63;
  const int w    = tid >> 6;          // 0..7
  const int wm = w >> 1, wn = w & 1;  // 4M x 2N

  // T1 XCD-aware decode
  const int bid = blockIdx.x;
  const int tq  = bid >> 3;
  const int m0  = ((bid & 7)*4 + (tq & 3)) * 256;
  const int r   = tq >> 2;
  const int n0  = (MODE == 0 ? (r & 7) : r) * 128;
  const int z   = (MODE == 0) ? (r >> 3) : 0;

  const unsigned short* W = Wb + (size_t)z * NW;
  unsigned short* Dh = (MODE == 0) ? ((z == 0) ? D0 : (z == 1) ? D1 : D2) : nullptr;
  const bool vtr = (MODE == 0) && (z == 2);

  f32x4 acc[4][4];
  #pragma unroll
  for (int i = 0; i < 4; ++i)
    #pragma unroll
    for (int j = 0; j < 4; ++j)
      acc[i][j] = (f32x4)0.0f;

  // staging: A 2 loads/thread, B 1 load/thread per K-tile (BK=32).
  auto stA = [&](int buf, int t, int l){
    const int id = l*512 + tid;                 // 0..1023
    const int row = id >> 2, c = id & 3;
    gload16(A + (size_t)(m0 + row)*DM + t*32 + ((c ^ ((row >> 1) & 3)) << 3),
            lds_ + buf*BSTR32 + id*16);
  };
  auto stB = [&](int buf, int t){
    const int id = tid;                         // 0..511
    const int row = id >> 2, c = id & 3;
    gload16(W + (size_t)(n0 + row)*DM + t*32 + ((c ^ ((row >> 1) & 3)) << 3),
            lds_ + buf*BSTR32 + ABUF32 + id*16);
  };
  auto ldA = [&](const char* Ab_, int i){
    const int row = wm*64 + i*16 + (lane & 15);
    const int c = (lane >> 4) ^ ((row >> 1) & 3);
    return *(const bf16x8*)(Ab_ + row*64 + (c << 4));
  };
  auto ldB = [&](const char* Bb_, int j){
    const int row = wn*64 + j*16 + (lane & 15);
    const int c = (lane >> 4) ^ ((row >> 1) & 3);
    return *(const bf16x8*)(Bb_ + row*64 + (c << 4));
  };

  // prologue: stage tiles 0,1 (3 loads each); wait tile 0 (oldest 3)
  stA(0, 0, 0); stA(0, 0, 1); stB(0, 0);
  stA(1, 1, 0); stA(1, 1, 1); stB(1, 1);
  asm volatile("s_waitcnt vmcnt(3)" ::: "memory");
  __builtin_amdgcn_s_barrier();

  int rb = 0, sb = 2;
  for (int t = 0; t < NT32; ++t){
    const char* Ab_ = lds_ + rb*BSTR32;
    const char* Bb_ = Ab_ + ABUF32;
    const bool st = (t + 2 < NT32);
    bf16x8 aF[4], bF[4];

    // all 8 fragment reads + prefetch issues, then one MFMA cluster
    aF[0] = ldA(Ab_, 0); aF[1] = ldA(Ab_, 1);
    aF[2] = ldA(Ab_, 2); aF[3] = ldA(Ab_, 3);
    bF[0] = ldB(Bb_, 0); bF[1] = ldB(Bb_, 1);
    bF[2] = ldB(Bb_, 2); bF[3] = ldB(Bb_, 3);
    if (st){ stA(sb, t+2, 0); stA(sb, t+2, 1); stB(sb, t+2); }
    __builtin_amdgcn_s_setprio(1);
    #pragma unroll
    for (int i = 0; i < 4; ++i)
      #pragma unroll
      for (int j = 0; j < 4; ++j)
        acc[i][j] = __builtin_amdgcn_mfma_f32_16x16x32_bf16(aF[i], bF[j], acc[i][j], 0, 0, 0);
    __builtin_amdgcn_s_setprio(0);
    if (t < NT32-2)       asm volatile("s_waitcnt vmcnt(3)" ::: "memory");
    else if (t == NT32-2) asm volatile("s_waitcnt vmcnt(0)" ::: "memory");
    if (t < NT32-1) __builtin_amdgcn_s_barrier();

    rb = (rb == 2) ? 0 : rb + 1;
    sb = (sb == 2) ? 0 : sb + 1;
  }

  // ---- epilogue: two 128x128 fp32 LDS halves (64KB) ----
  __syncthreads();
  float* T = (float*)lds_;
  #pragma unroll
  for (int h = 0; h < 2; ++h){
    if (h) __syncthreads();          // half0 reads done before half1 writes
    if ((wm >> 1) == h){
      #pragma unroll
      for (int i = 0; i < 4; ++i)
        #pragma unroll
        for (int j = 0; j < 4; ++j){
          const int n = wn*64 + j*16 + (lane & 15);
          #pragma unroll
          for (int rr = 0; rr < 4; ++rr){
            const int mh = (wm & 1)*64 + i*16 + ((lane >> 4) << 2) + rr;  // 0..127
            T[mh*128 + (n ^ ((mh & 7) << 2))] = acc[i][j][rr];
          }
        }
    }
    __syncthreads();
    if (MODE == 0 && vtr){
      // transposed coalesced V^T: thread owns column, 16B s-runs
      const int nl = tid >> 2;               // 0..127
      const int sblk = tid & 3;
      const int d = nl & 63, hh = (n0 >> 6) + (nl >> 6);
      const int bidx = m0 >> 11;
      unsigned short* vrow = Dh + (((size_t)(bidx*NH + hh))*DK + d)*SEQ
                               + (m0 & 2047) + h*128;
      #pragma unroll
      for (int c = 0; c < 4; ++c){
        const int s0 = sblk*8 + c*32;
        float v[8];
        #pragma unroll
        for (int j2 = 0; j2 < 8; ++j2)
          v[j2] = T[(s0 + j2)*128 + (nl ^ (((s0 + j2) & 7) << 2))];
        uint4 ov;
        ov.x = cvtpk(v[0], v[1]); ov.y = cvtpk(v[2], v[3]);
        ov.z = cvtpk(v[4], v[5]); ov.w = cvtpk(v[6], v[7]);
        *(uint4*)(vrow + s0) = ov;
      }
    } else {
      const float scale = (MODE == 0 && z == 0) ? QSCALE : 1.0f;
      #pragma unroll
      for (int k = 0; k < 4; ++k){
        const int cid = k*512 + tid;         // 0..2047
        const int d8   = cid & 7;            // 8-wide n-chunk within head
        const int sp_l = (cid >> 3) & 127;   // local row in half
        const int hc   = cid >> 10;          // head half (0/1)
        const int nb   = hc*64 + d8*8;
        const int sw   = (sp_l & 7) << 2;
        const f32x4 c0 = *(const f32x4*)&T[sp_l*128 + (nb ^ sw)];
        const f32x4 c1 = *(const f32x4*)&T[sp_l*128 + ((nb + 4) ^ sw)];
        if (MODE == 1){
          float* dst = Dout + (size_t)(m0 + h*128 + sp_l)*DM + n0 + nb;
          *(f32x4*)dst = c0;
          *(f32x4*)(dst + 4) = c1;
        } else {
          const int mg = m0 + h*128 + sp_l;
          const int bidx = mg >> 11, sp = mg & 2047;
          const float4 t01 = *(const float4*)&tab[(size_t)sp*64 + d8*8];
          const float4 t23 = *(const float4*)&tab[(size_t)sp*64 + d8*8 + 4];
          const unsigned int u0 = cvtpk((t01.x*c0[0] - t01.y*c0[1])*scale,
                                        (t01.y*c0[0] + t01.x*c0[1])*scale);
          const unsigned int u1 = cvtpk((t01.z*c0[2] - t01.w*c0[3])*scale,
                                        (t01.w*c0[2] + t01.z*c0[3])*scale);
          const unsigned int u2 = cvtpk((t23.x*c1[0] - t23.y*c1[1])*scale,
                                        (t23.y*c1[0] + t23.x*c1[1])*scale);
          const unsigned int u3 = cvtpk((t23.z*c1[2] - t23.w*c1[3])*scale,
                                        (t23.w*c1[2] + t23.z*c1[3])*scale);
          const int hh = (n0 >> 6) + hc;
          uint4 ov; ov.x = u0; ov.y = u1; ov.z = u2; ov.w = u3;
          *(uint4*)(Dh + ((size_t)((bidx*NH + hh)*SEQ + sp))*DK + d8*8) = ov;
        }
      }
    }
  }
}

// ============================================================
// Causal flash attention — swapped-QK^T 32x32 in-register softmax,
// kv-split dual-group blocks (8 waves, 512 threads), STATIC-MAX,
// v_exp_f32, XCD-pinned (bh,jj) grid. (frozen from R18)
// ============================================================
__global__ __launch_bounds__(512, 4) void k_attn(const unsigned short* __restrict__ Qh,
                                                 const unsigned short* __restrict__ Kh,
                                                 const unsigned short* __restrict__ Vt,
                                                 unsigned short* __restrict__ Ab)
{
  __shared__ uint4 ldsu[4096];   // 64 KiB: per-group [K0 8K|V0 8K][K1 8K|V1 8K]
  char* base = (char*)ldsu;
  const int tid  = threadIdx.x;
  const int lane = tid & 63;
  const int w    = tid >> 6;     // 0..7
  const int ww   = w & 3;        // wave-in-group
  const int g    = w >> 2;       // kv-half group
  const int tl   = tid & 255;    // thread-in-group
  const int l31  = lane & 31;
  const int hl   = lane >> 5;
  char* gb = base + g*32768;

  const int bh = blockIdx.x, jj = blockIdx.y;   // bh fast -> XCD-pinned KV
  const unsigned short* Qb = Qh + (size_t)bh*(SEQ*DK);
  const unsigned short* Kb = Kh + (size_t)bh*(SEQ*DK);
  const unsigned short* Vb = Vt + (size_t)bh*(SEQ*DK);
  const int b = bh >> 4, hd = bh & 15;

  for (int pass = 0; pass < 2; ++pass){
    const int qt = pass ? jj : 15 - jj;
    const int q0 = qt * 128;
    const int qbase = q0 + ww*32;

    bf16x8 qf[4];
    #pragma unroll
    for (int t = 0; t < 4; ++t)
      qf[t] = *(const bf16x8*)(Qb + (size_t)(qbase + l31)*DK + t*16 + hl*8);

    f32x16 acc0 = (f32x16)0.0f, acc1 = (f32x16)0.0f;
    float lsum = 0.0f;

    const int nk = qt + 1;
    const int tbase = g * nk;
    const int wqmax = qbase + 31;

    auto stage = [&](int buf, int ktile){
      const int k0s = ktile * 64;
      char* Kd = gb + buf*16384;
      char* Vd = Kd + 8192;
      #pragma unroll
      for (int cc = 0; cc < 2; ++cc){
        const int f = cc*256 + tl;
        const int r = f >> 3, slot = f & 7;
        const int sw = ((slot ^ (r & 7)) << 3);
        gload16(Kb + (size_t)(k0s + r)*DK + sw, Kd + (cc*256 + ww*64)*16);
        gload16(Vb + (size_t)r*SEQ + k0s + sw, Vd + (cc*256 + ww*64)*16);
      }
    };

    if (pass) __syncthreads();
    stage(0, tbase);
    __syncthreads();
    int cur = 0;

    for (int kt = 0; kt < nk; ++kt){
      const int k0 = (tbase + kt) * 64;
      if (kt + 1 < nk) stage(cur ^ 1, tbase + kt + 1);
      if (k0 <= wqmax){
        const char* Ks = gb + cur*16384;
        const char* Vs = Ks + 8192;

        f32x16 sv0 = (f32x16)0.0f, sv1 = (f32x16)0.0f;
        __builtin_amdgcn_s_setprio(1);
        #pragma unroll
        for (int t = 0; t < 4; ++t){
          const int colb = t*32 + hl*16;
          const bf16x8 a0 = ldsw(Ks, l31, colb);
          const bf16x8 a1 = ldsw(Ks, 32 + l31, colb);
          sv0 = __builtin_amdgcn_mfma_f32_32x32x16_bf16(a0, qf[t], sv0, 0, 0, 0);
          sv1 = __builtin_amdgcn_mfma_f32_32x32x16_bf16(a1, qf[t], sv1, 0, 0, 0);
        }
        __builtin_amdgcn_s_setprio(0);

        if (k0 + 63 > qbase){
          const int q = qbase + l31;
          #pragma unroll
          for (int j = 0; j < 16; ++j){
            const int kv = k0 + (j&3) + 8*(j>>2) + 4*hl;
            if (kv > q)      sv0[j] = -1e30f;
            if (kv + 32 > q) sv1[j] = -1e30f;
          }
        }

        #pragma unroll
        for (int j = 0; j < 16; ++j){
          sv0[j] = fexp2(sv0[j]);
          sv1[j] = fexp2(sv1[j]);
        }
        float ts[8];
        #pragma unroll
        for (int j = 0; j < 8; ++j)
          ts[j] = (sv0[j] + sv0[j+8]) + (sv1[j] + sv1[j+8]);
        #pragma unroll
        for (int off = 4; off; off >>= 1)
          #pragma unroll
          for (int j = 0; j < off; ++j)
            ts[j] += ts[j+off];
        lsum += ts[0] + __shfl_xor(ts[0], 32, 64);

        __builtin_amdgcn_s_setprio(1);
        #pragma unroll
        for (int t = 0; t < 4; ++t){
          f32x16& s = (t < 2) ? sv0 : sv1;
          const int b0v = (t & 1) * 8;
          const unsigned int A0 = cvtpk(s[b0v+0], s[b0v+1]);
          const unsigned int A1 = cvtpk(s[b0v+2], s[b0v+3]);
          const unsigned int B0 = cvtpk(s[b0v+4], s[b0v+5]);
          const unsigned int B1 = cvtpk(s[b0v+6], s[b0v+7]);
          const unsigned int s0 = hl ? A0 : B0;
          const unsigned int s1 = hl ? A1 : B1;
          const unsigned int r0 = (unsigned int)__shfl_xor((int)s0, 32, 64);
          const unsigned int r1 = (unsigned int)__shfl_xor((int)s1, 32, 64);
          union { unsigned int u[4]; bf16x8 v; } f;
          f.u[0] = hl ? r0 : A0; f.u[1] = hl ? r1 : A1;
          f.u[2] = hl ? B0 : r0; f.u[3] = hl ? B1 : r1;
          const int colb = t*32 + hl*16;
          const bf16x8 v0 = ldsw(Vs, l31, colb);
          const bf16x8 v1 = ldsw(Vs, 32 + l31, colb);
          acc0 = __builtin_amdgcn_mfma_f32_32x32x16_bf16(v0, f.v, acc0, 0, 0, 0);
          acc1 = __builtin_amdgcn_mfma_f32_32x32x16_bf16(v1, f.v, acc1, 0, 0, 0);
        }
        __builtin_amdgcn_s_setprio(0);
      }
      __syncthreads();
      cur ^= 1;
    }

    if (g == 1){
      char* cw = base + ww*9216 + lane*144;
      #pragma unroll
      for (int q4 = 0; q4 < 4; ++q4){
        *(f32x4*)(cw + q4*16)      = (f32x4){acc0[4*q4], acc0[4*q4+1], acc0[4*q4+2], acc0[4*q4+3]};
        *(f32x4*)(cw + 64 + q4*16) = (f32x4){acc1[4*q4], acc1[4*q4+1], acc1[4*q4+2], acc1[4*q4+3]};
      }
      *(float*)(cw + 128) = lsum;
    }
    __syncthreads();
    if (g == 0){
      const char* cr = base + ww*9216 + lane*144;
      const float l1 = *(const float*)(cr + 128);
      const float linv = 1.0f / (lsum + l1);
      unsigned short* orow = Ab + ((size_t)(b*SEQ + qbase + l31))*DM + hd*DK;
      #pragma unroll
      for (int mt = 0; mt < 2; ++mt){
        #pragma unroll
        for (int g4 = 0; g4 < 4; ++g4){
          const f32x16& a = mt ? acc1 : acc0;
          const f32x4 o = *(const f32x4*)(cr + mt*64 + g4*16);
          const unsigned int u0 = cvtpk((a[4*g4+0] + o[0])*linv, (a[4*g4+1] + o[1])*linv);
          const unsigned int u1 = cvtpk((a[4*g4+2] + o[2])*linv, (a[4*g4+3] + o[3])*linv);
          *(unsigned long long*)(orow + mt*32 + g4*8 + hl*4) =
              (unsigned long long)u0 | ((unsigned long long)u1 << 32);
        }
      }
    }
  }
}

// ============================================================
// launch
// ============================================================
extern "C" void kernel_launch(void* const* d_in, const int* in_sizes, int n_in,
                              void* d_out, int out_size, void* d_ws, size_t ws_size,
                              hipStream_t stream)
{
  (void)in_sizes; (void)n_in; (void)out_size;
  const float* x  = (const float*)d_in[0];
  const float* wq = (const float*)d_in[1];
  const float* wk = (const float*)d_in[2];
  const float* wv = (const float*)d_in[3];
  const float* wo = (const float*)d_in[4];
  const int* pos  = (const int*)d_in[5];
  float* out = (float*)d_out;

  // workspace layout (bytes); Ab (attn out) aliases xb (x no longer needed)
  if (ws_size < 92800000u) return;   // need ~88.5 MB
  char* ws = (char*)d_ws;
  unsigned short* xb = (unsigned short*)(ws);                 // 16 MB (also Ab)
  unsigned short* wb = (unsigned short*)(ws + 16777216);      //  8 MB (Wq|Wk|Wv|Wo)
  unsigned short* Qh = (unsigned short*)(ws + 25165824);      // 16 MB [b][h][s][d]
  unsigned short* Kh = (unsigned short*)(ws + 41943040);      // 16 MB
  unsigned short* Vt = (unsigned short*)(ws + 75497472);      // 16 MB [b][h][d][s]
  float* tab         = (float*)(ws + 92274688);               // 512 KB

  k_convert <<<6400, 256, 0, stream>>>(x, wq, wk, wv, wo, xb, wb, pos, tab);
  k_gemm<0> <<<768, 512, 0, stream>>>(xb, wb, Qh, Kh, Vt, nullptr, tab);
  k_attn    <<<dim3(64, 8), 512, 0, stream>>>(Qh, Kh, Vt, xb);
  k_gemm<1> <<<256, 512, 0, stream>>>(xb, wb + 3*NW, nullptr, nullptr,
                                      nullptr, out, nullptr);
}